// Round 4
// baseline (606.150 us; speedup 1.0000x reference)
//
#include <hip/hip_runtime.h>

// QLSTM: B=512, T=1024, IN=1, H=64.
// Block = 256 (4 waves), one batch element per block, grid 512 (2 blocks/CU).
// Wave w owns units [16w, 16w+16); lane l -> unit u = 16w + (l&15),
// gate gt = l>>4 (i,f,g,o), gate-row r = gt*64 + u. Each lane holds its full
// 64-weight row as 32 float2 -> 32 v_pk_fma_f32 per step.
//
// Per step: read h (broadcast b128 from shared hs[2][64], conflict-free),
// 32 pk_fma, one uniform activation a = m*sigmoid(s*acc)+d (tanh via
// m=s=2,d=-1), gather i,f,g,o within the wave via 3 shfl_xor + cndmask
// (NO LDS act exchange), redundant c/h update (4 lanes per unit), 16-lane
// h write, ONE barrier. Double-buffered hs by parity.

typedef float v2f __attribute__((ext_vector_type(2)));

#define TLEN 1024
#define HID  64

__device__ __forceinline__ float fast_sigmoid(float x) {
    return __builtin_amdgcn_rcpf(1.0f + __expf(-x));   // hw exp + hw rcp
}

__global__ __launch_bounds__(256, 2)
void qlstm_kernel(const float* __restrict__ x,      // [B, T, 1]
                  const float* __restrict__ W_ih,   // [256, 1]
                  const float* __restrict__ W_hh,   // [256, 64]
                  const float* __restrict__ b_ih,   // [256]
                  const float* __restrict__ b_hh,   // [256]
                  const float* __restrict__ W_lin,  // [1, 64]
                  const float* __restrict__ b_lin,  // [1]
                  float* __restrict__ out)          // [B]
{
    const int b    = blockIdx.x;
    const int tid  = threadIdx.x;
    const int w    = tid >> 6;        // wave 0..3
    const int l    = tid & 63;
    const int u16  = l & 15;          // unit within wave
    const int gt   = l >> 4;          // gate 0..3 (i,f,g,o)
    const int unit = w * 16 + u16;    // 0..63
    const int row  = gt * HID + unit; // gate-row 0..255

    __shared__ __align__(16) float xs[TLEN];      // 4 KB
    __shared__ __align__(16) float hs[2][HID];    // double-buffered h

    // Stage x row: 1024 floats, one float4 per thread.
    ((float4*)xs)[tid] = ((const float4*)(x + (size_t)b * TLEN))[tid];

    // This lane's weight row W_hh[row][0..63] as 32 float2.
    v2f w2[32];
    const v2f* Wr = (const v2f*)(W_hh + (size_t)row * HID);
    #pragma unroll
    for (int q = 0; q < 32; ++q) w2[q] = Wr[q];

    const float uw   = W_ih[row];                  // IN == 1
    const float bias = b_ih[row] + b_hh[row];

    // Uniform activation: a = m*sigmoid(s*acc)+d  (gate g uses tanh).
    const bool  isg = (gt == 2);
    const float s_  = isg ? 2.0f : 1.0f;
    const float m_  = isg ? 2.0f : 1.0f;
    const float d_  = isg ? -1.0f : 0.0f;
    const bool  lead = (gt == 0);   // lanes 0..15 publish h
    const bool  fi   = (gt < 2);    // select polarity for the gather

    float c = 0.0f;
    if (tid < HID) hs[0][tid] = 0.0f;
    __syncthreads();   // xs + hs[0] ready

    for (int t = 0; t < TLEN; ++t) {
        const int p = t & 1;
        const float xt = xs[t];                       // same-address broadcast
        const float base = __builtin_fmaf(xt, uw, bias);

        // acc = W_hh[row,:] . h  (+ base), 32 pk_fma in 4 chains.
        v2f a0 = {base, 0.0f}, a1 = {0.0f, 0.0f}, a2 = {0.0f, 0.0f}, a3 = {0.0f, 0.0f};
        const float4* hp = (const float4*)&hs[p][0];  // broadcast reads
        #pragma unroll
        for (int q = 0; q < 16; q += 2) {
            const float4 h0 = hp[q];
            const float4 h1 = hp[q + 1];
            const v2f hA = {h0.x, h0.y}, hB = {h0.z, h0.w};
            const v2f hC = {h1.x, h1.y}, hD = {h1.z, h1.w};
            a0 = __builtin_elementwise_fma(hA, w2[2 * q + 0], a0);
            a1 = __builtin_elementwise_fma(hB, w2[2 * q + 1], a1);
            a2 = __builtin_elementwise_fma(hC, w2[2 * q + 2], a2);
            a3 = __builtin_elementwise_fma(hD, w2[2 * q + 3], a3);
        }
        const v2f s2 = (a0 + a1) + (a2 + a3);
        const float acc = s2.x + s2.y;

        // This lane's gate activation (uniform code, no divergence).
        const float a = __builtin_fmaf(m_, fast_sigmoid(s_ * acc), d_);

        // Gather i,f,g,o for this lane's unit: lanes u16, +16, +32, +48.
        const float b16  = __shfl_xor(a, 16, 64);
        const float lo   = (gt & 1) ? b16 : a;    // even gate of the pair
        const float hi   = (gt & 1) ? a   : b16;  // odd gate of the pair
        const float lo32 = __shfl_xor(lo, 32, 64);
        const float hi32 = __shfl_xor(hi, 32, 64);
        const float ig = fi ? lo   : lo32;
        const float fg = fi ? hi   : hi32;
        const float gg = fi ? lo32 : lo;
        const float og = fi ? hi32 : hi;

        // Redundant c/h update (4 lanes per unit stay in lockstep).
        c = __builtin_fmaf(fg, c, ig * gg);
        const float th = __builtin_fmaf(2.0f, fast_sigmoid(2.0f * c), -1.0f);
        const float h  = og * th;
        if (lead) hs[p ^ 1][unit] = h;            // 16-lane stride-1 write

        __syncthreads();                          // the ONE barrier per step
    }

    // t=1023 wrote hs[0]. out[b] = dot(h, W_lin) + b_lin (wave 0 only).
    if (w == 0) {
        float v = hs[0][l] * W_lin[l];
        #pragma unroll
        for (int off = 32; off > 0; off >>= 1)
            v += __shfl_down(v, off, 64);
        if (l == 0) out[b] = v + b_lin[0];
    }
}

extern "C" void kernel_launch(void* const* d_in, const int* in_sizes, int n_in,
                              void* d_out, int out_size, void* d_ws, size_t ws_size,
                              hipStream_t stream) {
    const float* x     = (const float*)d_in[0];
    const float* W_ih  = (const float*)d_in[1];
    const float* W_hh  = (const float*)d_in[2];
    const float* b_ih  = (const float*)d_in[3];
    const float* b_hh  = (const float*)d_in[4];
    const float* W_lin = (const float*)d_in[5];
    const float* b_lin = (const float*)d_in[6];
    float* out = (float*)d_out;

    const int B = out_size;  // 512
    qlstm_kernel<<<B, 256, 0, stream>>>(x, W_ih, W_hh, b_ih, b_hh, W_lin, b_lin, out);
}